// Round 1
// baseline (299.088 us; speedup 1.0000x reference)
//
#include <hip/hip_runtime.h>

// LocalConnectivity: diamond (L1-ball radius 5) circular convolution over
// (B=64, H=512, W=512) fp32, weight per L1-distance d: w_d = d_in[1][d-1].
//
// Decomposition (exact for arbitrary w):
//   h_a[r][j] = sum_{|b| <= 5-a} w_{a+|b|} * s[r][(j-b)&511]   (h_0 excludes b=0)
//   out[i][j] = h_0[i][j] + sum_{a=1..5} (h_a[i-a][j] + h_a[i+a][j])
//
// Thread owns 4 consecutive columns; block of 128 threads covers full W=512
// (x-wraparound via &511 => no LDS halo needed). Each block processes a strip
// of TY=16 output rows, streaming source rows (TY+10 of them, wraparound via
// &511) with an 11-slot rolling accumulator ring. No LDS, no barriers; the 5
// overlapping float4 loads per row hit L1/L2.

#define LC_H 512
#define LC_W 512
#define LC_TY 16
#define LC_NT 128  // threads per block; each owns 4 columns

__global__ __launch_bounds__(LC_NT, 4)
void LocalConnectivity_kernel(const float* __restrict__ in,
                              const float* __restrict__ wp,
                              float* __restrict__ out) {
    const int t = threadIdx.x;            // column-block index 0..127
    const int b = blockIdx.y;             // batch
    const int r0 = blockIdx.x * LC_TY;    // first output row of strip

    const float w1 = wp[0], w2 = wp[1], w3 = wp[2], w4 = wp[3], w5 = wp[4];

    const float* __restrict__ src = in + (size_t)b * LC_H * LC_W;
    float* __restrict__ dst = out + (size_t)b * LC_H * LC_W;

    float acc[11][4];
#pragma unroll
    for (int k = 0; k < 11; ++k)
#pragma unroll
        for (int q = 0; q < 4; ++q) acc[k][q] = 0.f;

#pragma unroll
    for (int rr = 0; rr < LC_TY + 10; ++rr) {
        const int r_off = rr - 5;  // source row relative to r0
        const int row = (r0 + r_off) & (LC_H - 1);
        const float* rowp = src + row * LC_W;

        // Load 20 columns: global cols 4t-8 .. 4t+11 as 5 aligned float4s.
        float v[20];
#pragma unroll
        for (int o = 0; o < 5; ++o) {
            const int cb = (t + o - 2) & (LC_NT - 1);
            const float4 f = *reinterpret_cast<const float4*>(rowp + cb * 4);
            v[o * 4 + 0] = f.x;
            v[o * 4 + 1] = f.y;
            v[o * 4 + 2] = f.z;
            v[o * 4 + 3] = f.w;
        }

        // Horizontal pass: h_a for my 4 columns. v[k] = col (4t + k - 8),
        // so column q (global 4t+q) has offset b at v[8+q-b] / v[8+q+b].
        float h[6][4];
#pragma unroll
        for (int q = 0; q < 4; ++q) {
            const float p0 = v[8 + q];
            const float p1 = v[7 + q] + v[9 + q];
            const float p2 = v[6 + q] + v[10 + q];
            const float p3 = v[5 + q] + v[11 + q];
            const float p4 = v[4 + q] + v[12 + q];
            const float p5 = v[3 + q] + v[13 + q];
            h[0][q] = w1 * p1 + w2 * p2 + w3 * p3 + w4 * p4 + w5 * p5;
            h[1][q] = w1 * p0 + w2 * p1 + w3 * p2 + w4 * p3 + w5 * p4;
            h[2][q] = w2 * p0 + w3 * p1 + w4 * p2 + w5 * p3;
            h[3][q] = w3 * p0 + w4 * p1 + w5 * p2;
            h[4][q] = w4 * p0 + w5 * p1;
            h[5][q] = w5 * p0;
        }

        // Vertical accumulation: source row r contributes h_a to outputs
        // r-a and r+a (h_0 to r). All guards fold at compile time (rr const).
#pragma unroll
        for (int a = 0; a <= 5; ++a) {
            const int o_p = r_off + a;
            if (o_p >= 0 && o_p < LC_TY) {
#pragma unroll
                for (int q = 0; q < 4; ++q) acc[o_p % 11][q] += h[a][q];
            }
            if (a > 0) {
                const int o_m = r_off - a;
                if (o_m >= 0 && o_m < LC_TY) {
#pragma unroll
                    for (int q = 0; q < 4; ++q) acc[o_m % 11][q] += h[a][q];
                }
            }
        }

        // Output row oc = rr - 10 is complete after this source row.
        const int oc = rr - 10;
        if (oc >= 0 && oc < LC_TY) {
            const int slot = oc % 11;
            float4 f;
            f.x = acc[slot][0];
            f.y = acc[slot][1];
            f.z = acc[slot][2];
            f.w = acc[slot][3];
            *reinterpret_cast<float4*>(dst + (r0 + oc) * LC_W + t * 4) = f;
#pragma unroll
            for (int q = 0; q < 4; ++q) acc[slot][q] = 0.f;
        }
    }
}

extern "C" void kernel_launch(void* const* d_in, const int* in_sizes, int n_in,
                              void* d_out, int out_size, void* d_ws, size_t ws_size,
                              hipStream_t stream) {
    const float* grid_spikes = (const float*)d_in[0];       // 64*512*512 fp32
    const float* distance_weights = (const float*)d_in[1];  // 5 fp32
    float* out = (float*)d_out;

    dim3 grid(LC_H / LC_TY, 64);  // 32 strips x 64 batches
    dim3 block(LC_NT);
    LocalConnectivity_kernel<<<grid, block, 0, stream>>>(grid_spikes, distance_weights, out);
}

// Round 2
// 130.437 us; speedup vs baseline: 2.2930x; 2.2930x over previous
//
#include <hip/hip_runtime.h>

// LocalConnectivity: diamond (L1-ball radius 5) circular convolution over
// (B=64, H=512, W=512) fp32, weight per L1-distance d: w_d = d_in[1][d-1].
//
// Decomposition (exact for arbitrary w):
//   h_a[r][j] = sum_{|b| <= 5-a} w_{a+|b|} * s[r][(j-b)&511]   (h_0 excludes b=0)
//   out[i][j] = h_0[i][j] + sum_{a=1..5} (h_a[i-a][j] + h_a[i+a][j])
//
// Thread owns 4 consecutive columns; block of 128 threads covers full W=512
// (x-wraparound via &511 => no LDS halo needed). Each block processes a strip
// of TY=16 output rows, streaming source rows (TY+10 of them, wraparound via
// &511) with an 11-slot rolling accumulator ring. No LDS, no barriers; the 5
// overlapping float4 loads per row hit L1/L2.
//
// R1 lesson: __launch_bounds__(128,4) capped VGPRs at 64 -> the ~100-float
// live set spilled to scratch -> 724 MB HBM traffic (5.4x ideal), 217 us.
// Fix: no waves-per-EU bound; let the allocator use the full VGPR budget.

#define LC_H 512
#define LC_W 512
#define LC_TY 16
#define LC_NT 128  // threads per block; each owns 4 columns

__global__ __launch_bounds__(LC_NT)
void LocalConnectivity_kernel(const float* __restrict__ in,
                              const float* __restrict__ wp,
                              float* __restrict__ out) {
    const int t = threadIdx.x;            // column-block index 0..127
    const int b = blockIdx.y;             // batch
    const int r0 = blockIdx.x * LC_TY;    // first output row of strip

    const float w1 = wp[0], w2 = wp[1], w3 = wp[2], w4 = wp[3], w5 = wp[4];

    const float* __restrict__ src = in + (size_t)b * LC_H * LC_W;
    float* __restrict__ dst = out + (size_t)b * LC_H * LC_W;

    float acc[11][4];
#pragma unroll
    for (int k = 0; k < 11; ++k)
#pragma unroll
        for (int q = 0; q < 4; ++q) acc[k][q] = 0.f;

#pragma unroll
    for (int rr = 0; rr < LC_TY + 10; ++rr) {
        const int r_off = rr - 5;  // source row relative to r0
        const int row = (r0 + r_off) & (LC_H - 1);
        const float* rowp = src + row * LC_W;

        // Load 20 columns: global cols 4t-8 .. 4t+11 as 5 aligned float4s.
        float v[20];
#pragma unroll
        for (int o = 0; o < 5; ++o) {
            const int cb = (t + o - 2) & (LC_NT - 1);
            const float4 f = *reinterpret_cast<const float4*>(rowp + cb * 4);
            v[o * 4 + 0] = f.x;
            v[o * 4 + 1] = f.y;
            v[o * 4 + 2] = f.z;
            v[o * 4 + 3] = f.w;
        }

        // Horizontal pass: h_a for my 4 columns. v[k] = col (4t + k - 8),
        // so column q (global 4t+q) has offset b at v[8+q-b] / v[8+q+b].
        float h[6][4];
#pragma unroll
        for (int q = 0; q < 4; ++q) {
            const float p0 = v[8 + q];
            const float p1 = v[7 + q] + v[9 + q];
            const float p2 = v[6 + q] + v[10 + q];
            const float p3 = v[5 + q] + v[11 + q];
            const float p4 = v[4 + q] + v[12 + q];
            const float p5 = v[3 + q] + v[13 + q];
            h[0][q] = w1 * p1 + w2 * p2 + w3 * p3 + w4 * p4 + w5 * p5;
            h[1][q] = w1 * p0 + w2 * p1 + w3 * p2 + w4 * p3 + w5 * p4;
            h[2][q] = w2 * p0 + w3 * p1 + w4 * p2 + w5 * p3;
            h[3][q] = w3 * p0 + w4 * p1 + w5 * p2;
            h[4][q] = w4 * p0 + w5 * p1;
            h[5][q] = w5 * p0;
        }

        // Vertical accumulation: source row r contributes h_a to outputs
        // r-a and r+a (h_0 to r). All guards fold at compile time (rr const).
#pragma unroll
        for (int a = 0; a <= 5; ++a) {
            const int o_p = r_off + a;
            if (o_p >= 0 && o_p < LC_TY) {
#pragma unroll
                for (int q = 0; q < 4; ++q) acc[o_p % 11][q] += h[a][q];
            }
            if (a > 0) {
                const int o_m = r_off - a;
                if (o_m >= 0 && o_m < LC_TY) {
#pragma unroll
                    for (int q = 0; q < 4; ++q) acc[o_m % 11][q] += h[a][q];
                }
            }
        }

        // Output row oc = rr - 10 is complete after this source row.
        const int oc = rr - 10;
        if (oc >= 0 && oc < LC_TY) {
            const int slot = oc % 11;
            float4 f;
            f.x = acc[slot][0];
            f.y = acc[slot][1];
            f.z = acc[slot][2];
            f.w = acc[slot][3];
            *reinterpret_cast<float4*>(dst + (r0 + oc) * LC_W + t * 4) = f;
#pragma unroll
            for (int q = 0; q < 4; ++q) acc[slot][q] = 0.f;
        }
    }
}

extern "C" void kernel_launch(void* const* d_in, const int* in_sizes, int n_in,
                              void* d_out, int out_size, void* d_ws, size_t ws_size,
                              hipStream_t stream) {
    const float* grid_spikes = (const float*)d_in[0];       // 64*512*512 fp32
    const float* distance_weights = (const float*)d_in[1];  // 5 fp32
    float* out = (float*)d_out;

    dim3 grid(LC_H / LC_TY, 64);  // 32 strips x 64 batches
    dim3 block(LC_NT);
    LocalConnectivity_kernel<<<grid, block, 0, stream>>>(grid_spikes, distance_weights, out);
}

// Round 3
// 120.379 us; speedup vs baseline: 2.4846x; 1.0836x over previous
//
#include <hip/hip_runtime.h>

// LocalConnectivity: diamond (L1-ball radius 5) circular convolution over
// (B=64, H=512, W=512) fp32, weight per L1-distance d: w_d = d_in[1][d-1].
//
// Decomposition (exact):
//   h_a[r][j] = sum_{|b| <= 5-a} w_{a+|b|} * s[r][(j+b)&511]   (h_0 excludes b=0)
//   out[i][j] = h_0[i][j] + sum_{a=1..5} (h_a[i-a][j] + h_a[i+a][j])
//
// R1 lesson: __launch_bounds__(128,4) -> 64 VGPR cap -> scratch spills ->
//   724 MB HBM, 217 us. R2 (no cap, direct global reads): 67 us rocprof,
//   but latency-bound (VALU 13.5%, HBM 23%): 130 global loads/thread, 80%
//   L1 re-reads, not enough MLP at 4 waves/SIMD.
// R3: LDS row-pipeline. Each thread loads its own float4 of each source row
//   ONCE (26 loads), stages into a 6-slot LDS row ring (12 KB), reads the
//   20-col halo window from LDS. One barrier/iter; write-ahead A=3 slots,
//   global prefetch distance 2 iters. Hazards: slot written at iter rr was
//   last read at iter rr-3 (>=1 barrier apart); slot read at iter rr was
//   written at iter rr-3. All ring/guard indices fold at compile time via
//   full unroll.

#define LC_H 512
#define LC_W 512
#define LC_TY 16
#define LC_NT 128   // threads per block; each owns 4 columns
#define LC_NR (LC_TY + 10)  // 26 source rows per strip
#define LC_RS 6     // LDS ring slots

__global__ __launch_bounds__(LC_NT)
void LocalConnectivity_kernel(const float* __restrict__ in,
                              const float* __restrict__ wp,
                              float* __restrict__ out) {
    const int t = threadIdx.x;            // column-block index 0..127
    const int b = blockIdx.y;             // batch
    const int r0 = blockIdx.x * LC_TY;    // first output row of strip

    const float w1 = wp[0], w2 = wp[1], w3 = wp[2], w4 = wp[3], w5 = wp[4];

    const float* __restrict__ src = in + (size_t)b * LC_H * LC_W;
    float* __restrict__ dst = out + (size_t)b * LC_H * LC_W;

    __shared__ float lds[LC_RS * LC_W];   // 12 KB: ring of 6 source rows

    // source row j (0..25) lives at grid row (r0 + j - 5) & 511, LDS slot j%6
    auto row_ptr = [&](int j) -> const float* {
        return src + ((r0 + j - 5) & (LC_H - 1)) * LC_W;
    };

    float acc[11][4];
#pragma unroll
    for (int k = 0; k < 11; ++k)
#pragma unroll
        for (int q = 0; q < 4; ++q) acc[k][q] = 0.f;

    // ---- pipeline prologue: rows 0..2 -> LDS slots 0..2; rows 3,4 -> regs
    float4 fpre[3];
#pragma unroll
    for (int j = 0; j < 3; ++j) {
        const float4 f = *reinterpret_cast<const float4*>(row_ptr(j) + t * 4);
        *reinterpret_cast<float4*>(&lds[j * LC_W + t * 4]) = f;
    }
    fpre[1] = *reinterpret_cast<const float4*>(row_ptr(3) + t * 4);
    fpre[2] = *reinterpret_cast<const float4*>(row_ptr(4) + t * 4);

#pragma unroll
    for (int rr = 0; rr < LC_NR; ++rr) {
        __syncthreads();

        // stage row rr+3 (loaded 2 iters ago) into slot (rr+3)%6
        if (rr + 3 < LC_NR) {
            const float4 f = fpre[(rr + 1) % 3];
            *reinterpret_cast<float4*>(&lds[((rr + 3) % LC_RS) * LC_W + t * 4]) = f;
        }
        // prefetch row rr+5 from global (consumed at iter rr+2)
        if (rr + 5 < LC_NR) {
            fpre[rr % 3] = *reinterpret_cast<const float4*>(row_ptr(rr + 5) + t * 4);
        }

        // read 20 columns (cols 4t-8 .. 4t+11) of source row rr from LDS
        float v[20];
        const float* slotp = &lds[(rr % LC_RS) * LC_W];
#pragma unroll
        for (int o = 0; o < 5; ++o) {
            const int cb = (t + o - 2) & (LC_NT - 1);
            const float4 f = *reinterpret_cast<const float4*>(slotp + cb * 4);
            v[o * 4 + 0] = f.x;
            v[o * 4 + 1] = f.y;
            v[o * 4 + 2] = f.z;
            v[o * 4 + 3] = f.w;
        }

        // horizontal pass: v[8+q] is my column q (global 4t+q)
        float h[6][4];
#pragma unroll
        for (int q = 0; q < 4; ++q) {
            const float p0 = v[8 + q];
            const float p1 = v[7 + q] + v[9 + q];
            const float p2 = v[6 + q] + v[10 + q];
            const float p3 = v[5 + q] + v[11 + q];
            const float p4 = v[4 + q] + v[12 + q];
            const float p5 = v[3 + q] + v[13 + q];
            h[0][q] = w1 * p1 + w2 * p2 + w3 * p3 + w4 * p4 + w5 * p5;
            h[1][q] = w1 * p0 + w2 * p1 + w3 * p2 + w4 * p3 + w5 * p4;
            h[2][q] = w2 * p0 + w3 * p1 + w4 * p2 + w5 * p3;
            h[3][q] = w3 * p0 + w4 * p1 + w5 * p2;
            h[4][q] = w4 * p0 + w5 * p1;
            h[5][q] = w5 * p0;
        }

        // vertical scatter: source row rr contributes h_a to outputs r_off±a
        const int r_off = rr - 5;
#pragma unroll
        for (int a = 0; a <= 5; ++a) {
            const int o_p = r_off + a;
            if (o_p >= 0 && o_p < LC_TY) {
#pragma unroll
                for (int q = 0; q < 4; ++q) acc[o_p % 11][q] += h[a][q];
            }
            if (a > 0) {
                const int o_m = r_off - a;
                if (o_m >= 0 && o_m < LC_TY) {
#pragma unroll
                    for (int q = 0; q < 4; ++q) acc[o_m % 11][q] += h[a][q];
                }
            }
        }

        // output row oc = rr - 10 complete after this source row
        const int oc = rr - 10;
        if (oc >= 0 && oc < LC_TY) {
            const int slot = oc % 11;
            float4 f;
            f.x = acc[slot][0];
            f.y = acc[slot][1];
            f.z = acc[slot][2];
            f.w = acc[slot][3];
            *reinterpret_cast<float4*>(dst + (r0 + oc) * LC_W + t * 4) = f;
#pragma unroll
            for (int q = 0; q < 4; ++q) acc[slot][q] = 0.f;
        }
    }
}

extern "C" void kernel_launch(void* const* d_in, const int* in_sizes, int n_in,
                              void* d_out, int out_size, void* d_ws, size_t ws_size,
                              hipStream_t stream) {
    const float* grid_spikes = (const float*)d_in[0];       // 64*512*512 fp32
    const float* distance_weights = (const float*)d_in[1];  // 5 fp32
    float* out = (float*)d_out;

    dim3 grid(LC_H / LC_TY, 64);  // 32 strips x 64 batches
    dim3 block(LC_NT);
    LocalConnectivity_kernel<<<grid, block, 0, stream>>>(grid_spikes, distance_weights, out);
}